// Round 1
// baseline (679.248 us; speedup 1.0000x reference)
//
#include <hip/hip_runtime.h>
#include <math.h>

#define B_ 128
#define N_ 2048
#define D_ 256
#define NHEADS 32   // 2 head-sets * 16 heads

// ws layout (float offsets)
#define POOLED_OFF 0                         // B*D = 32768
#define P_OFF      32768                     // B*32*256 = 1048576
#define LOG_OFF    1081344                   // B*32*2048 = 8388608
#define FEATP_OFF  9469952                   // 4*B*32*256 = 4194304  (total ~54.7 MB)

__device__ __forceinline__ void atomic_max_f32(float* addr, float v) {
    if (v >= 0.0f) {
        atomicMax((int*)addr, __float_as_int(v + 0.0f));   // +0.0f maps -0 -> +0
    } else {
        atomicMin((unsigned int*)addr, __float_as_uint(v));
    }
}

__global__ __launch_bounds__(256) void k_init(float* __restrict__ pooled) {
    pooled[blockIdx.x * 256 + threadIdx.x] = -INFINITY;
}

// global max-pool per graph: grid = B*16, block handles 128 rows, thread-per-column
__global__ __launch_bounds__(256) void k_pool(const float* __restrict__ inp,
                                              float* __restrict__ pooled) {
    int b = blockIdx.x >> 4;
    int chunk = blockIdx.x & 15;
    int d = threadIdx.x;
    const float* p = inp + ((size_t)(b * N_ + chunk * 128)) * D_ + d;
    float m = -INFINITY;
#pragma unroll 8
    for (int i = 0; i < 128; ++i) m = fmaxf(m, p[(size_t)i * D_]);
    atomic_max_f32(pooled + b * D_ + d, m);
}

// q = pooled @ Wq^T (both sets), then P[b][j][d] = sum_k q[j][k] * Wk[k][d]
__global__ __launch_bounds__(256) void k_qp(const float* __restrict__ pooled,
                                            const float* __restrict__ Wq0,
                                            const float* __restrict__ Wq1,
                                            const float* __restrict__ Wk,
                                            float* __restrict__ P) {
    __shared__ float pl[D_];
    __shared__ float ql[1024];
    int b = blockIdx.x, t = threadIdx.x;
    pl[t] = pooled[b * D_ + t];
    __syncthreads();
    for (int rep = 0; rep < 4; ++rep) {
        int idx = rep * 256 + t;                 // 0..1023
        const float* Wq = (idx < 512) ? Wq0 : Wq1;
        int row = idx & 511;
        const float4* wr = (const float4*)(Wq + (size_t)row * D_);
        float acc = 0.0f;
        for (int dq = 0; dq < 64; ++dq) {
            float4 w = wr[dq];
            const float* pp = &pl[dq * 4];
            acc += w.x * pp[0] + w.y * pp[1] + w.z * pp[2] + w.w * pp[3];
        }
        ql[idx] = acc;
    }
    __syncthreads();
    float wk[32];
#pragma unroll
    for (int k = 0; k < 32; ++k) wk[k] = Wk[k * D_ + t];
    for (int j = 0; j < NHEADS; ++j) {
        const float* q = &ql[(j >> 4) * 512 + (j & 15) * 32];
        float acc = 0.0f;
#pragma unroll
        for (int k = 0; k < 32; ++k) acc = fmaf(q[k], wk[k], acc);
        P[((size_t)b * NHEADS + j) * D_ + t] = acc;
    }
}

// logits[b][j][n] = sum_d P[b][j][d] * x[b][n][d]
// block tile: 512 n x 32 j, K chunked by 16; thread: 8n (stride 64) x 8j (stride 4)
__global__ __launch_bounds__(256) void k_logits(const float* __restrict__ inp,
                                                const float* __restrict__ P,
                                                float* __restrict__ logits) {
    __shared__ float xs[512 * 20];   // [n][16 + 4 pad]
    __shared__ float ps[NHEADS * 20];
    int b = blockIdx.x >> 2, nt = blockIdx.x & 3;
    int n0 = nt * 512;
    int t = threadIdx.x;
    int jg = t & 3, ng = t >> 2;                 // j = jg + 4*jj ; n = ng + 64*k
    float acc[8][8] = {};                        // [jj][k]
    const float* xbase = inp + ((size_t)(b * N_ + n0)) * D_;
    const float* pbase = P + (size_t)b * NHEADS * D_;
    for (int c = 0; c < 16; ++c) {
        int d0 = c * 16;
        {   // stage x: 512 rows x 16 d
            int q = t & 3, nrow = t >> 2;
            for (int k = 0; k < 8; ++k) {
                int n = nrow + k * 64;
                float4 v = *(const float4*)(xbase + (size_t)n * D_ + d0 + q * 4);
                *(float4*)&xs[n * 20 + q * 4] = v;
            }
            if (t < 128) {
                int j = t >> 2;
                float4 v = *(const float4*)(pbase + (size_t)j * D_ + d0 + q * 4);
                *(float4*)&ps[j * 20 + q * 4] = v;
            }
        }
        __syncthreads();
#pragma unroll
        for (int dd = 0; dd < 16; dd += 4) {
            float4 xa[8], pa[8];
#pragma unroll
            for (int k = 0; k < 8; ++k)
                xa[k] = *(const float4*)&xs[(ng + 64 * k) * 20 + dd];
#pragma unroll
            for (int jj = 0; jj < 8; ++jj)
                pa[jj] = *(const float4*)&ps[(jg + 4 * jj) * 20 + dd];
#pragma unroll
            for (int jj = 0; jj < 8; ++jj)
#pragma unroll
                for (int k = 0; k < 8; ++k)
                    acc[jj][k] += xa[k].x * pa[jj].x + xa[k].y * pa[jj].y +
                                  xa[k].z * pa[jj].z + xa[k].w * pa[jj].w;
        }
        __syncthreads();
    }
#pragma unroll
    for (int jj = 0; jj < 8; ++jj) {
        int j = jg + 4 * jj;
        float* lb = logits + ((size_t)b * NHEADS + j) * N_ + n0 + ng;
#pragma unroll
        for (int k = 0; k < 8; ++k) lb[64 * k] = acc[jj][k];   // lanes contiguous in ng
    }
}

// softmax over n per (b, j) row, in place
__global__ __launch_bounds__(256) void k_softmax(float* __restrict__ logits) {
    float* row = logits + (size_t)blockIdx.x * N_;
    int t = threadIdx.x;
    float4 v0 = *(const float4*)(row + t * 8);
    float4 v1 = *(const float4*)(row + t * 8 + 4);
    float m = fmaxf(fmaxf(fmaxf(v0.x, v0.y), fmaxf(v0.z, v0.w)),
                    fmaxf(fmaxf(v1.x, v1.y), fmaxf(v1.z, v1.w)));
#pragma unroll
    for (int off = 32; off; off >>= 1) m = fmaxf(m, __shfl_xor(m, off, 64));
    __shared__ float smax[4];
    __shared__ float ssum[4];
    int wid = t >> 6;
    if ((t & 63) == 0) smax[wid] = m;
    __syncthreads();
    m = fmaxf(fmaxf(smax[0], smax[1]), fmaxf(smax[2], smax[3]));
    float w[8];
    w[0] = __expf(v0.x - m); w[1] = __expf(v0.y - m);
    w[2] = __expf(v0.z - m); w[3] = __expf(v0.w - m);
    w[4] = __expf(v1.x - m); w[5] = __expf(v1.y - m);
    w[6] = __expf(v1.z - m); w[7] = __expf(v1.w - m);
    float s = 0.0f;
#pragma unroll
    for (int i = 0; i < 8; ++i) s += w[i];
#pragma unroll
    for (int off = 32; off; off >>= 1) s += __shfl_xor(s, off, 64);
    if ((t & 63) == 0) ssum[wid] = s;
    __syncthreads();
    s = ssum[0] + ssum[1] + ssum[2] + ssum[3];
    float inv = 1.0f / s;
    float4 o0 = {w[0] * inv, w[1] * inv, w[2] * inv, w[3] * inv};
    float4 o1 = {w[4] * inv, w[5] * inv, w[6] * inv, w[7] * inv};
    *(float4*)(row + t * 8) = o0;
    *(float4*)(row + t * 8 + 4) = o1;
}

// feat partials: featp[ns][b][j][d] = sum_{n in split ns} att[b][j][n] * x[b][n][d]
// grid = B*4; block tile 32j x 256d; thread: 4j x 8d (d = dg*4+i and 128+dg*4+i)
__global__ __launch_bounds__(256) void k_feat(const float* __restrict__ inp,
                                              const float* __restrict__ att,
                                              float* __restrict__ featp) {
    __shared__ float xs[32 * 256];
    __shared__ float as_[32 * 36];
    int b = blockIdx.x >> 2, ns = blockIdx.x & 3;
    int n0 = ns * 512;
    int t = threadIdx.x;
    int dg = t & 31, jg = t >> 5;                     // j = jg*4 + jj
    float4 accA[4] = {};
    float4 accB[4] = {};
    const float* xb = inp + ((size_t)(b * N_ + n0)) * D_;
    const float* ab = att + (size_t)b * NHEADS * N_ + n0;
    for (int c = 0; c < 16; ++c) {
        {   // stage 32 rows of x
            int q = t & 63, row = t >> 6;
            for (int k = 0; k < 8; ++k) {
                int n = row + k * 4;
                *(float4*)&xs[n * 256 + q * 4] =
                    *(const float4*)(xb + (size_t)(c * 32 + n) * D_ + q * 4);
            }
            int j = t >> 3, qq = t & 7;
            *(float4*)&as_[j * 36 + qq * 4] =
                *(const float4*)(ab + (size_t)j * N_ + c * 32 + qq * 4);
        }
        __syncthreads();
#pragma unroll
        for (int nn = 0; nn < 32; nn += 4) {
            float4 aa[4];
#pragma unroll
            for (int jj = 0; jj < 4; ++jj)
                aa[jj] = *(const float4*)&as_[(jg * 4 + jj) * 36 + nn];
#pragma unroll
            for (int i4 = 0; i4 < 4; ++i4) {
                int n = nn + i4;
                float4 xA = *(const float4*)&xs[n * 256 + dg * 4];
                float4 xB = *(const float4*)&xs[n * 256 + 128 + dg * 4];
#pragma unroll
                for (int jj = 0; jj < 4; ++jj) {
                    float a = (i4 == 0) ? aa[jj].x : (i4 == 1) ? aa[jj].y
                            : (i4 == 2) ? aa[jj].z : aa[jj].w;
                    accA[jj].x = fmaf(a, xA.x, accA[jj].x);
                    accA[jj].y = fmaf(a, xA.y, accA[jj].y);
                    accA[jj].z = fmaf(a, xA.z, accA[jj].z);
                    accA[jj].w = fmaf(a, xA.w, accA[jj].w);
                    accB[jj].x = fmaf(a, xB.x, accB[jj].x);
                    accB[jj].y = fmaf(a, xB.y, accB[jj].y);
                    accB[jj].z = fmaf(a, xB.z, accB[jj].z);
                    accB[jj].w = fmaf(a, xB.w, accB[jj].w);
                }
            }
        }
        __syncthreads();
    }
    float* fb = featp + ((size_t)ns * B_ + b) * NHEADS * D_;
#pragma unroll
    for (int jj = 0; jj < 4; ++jj) {
        int j = jg * 4 + jj;
        *(float4*)(fb + (size_t)j * D_ + dg * 4) = accA[jj];
        *(float4*)(fb + (size_t)j * D_ + 128 + dg * 4) = accB[jj];
    }
}

// epilogue: reduce partials, bhr = feat@We^T, dx = set0-set1, out = dx@Wout^T + bias, leaky
__global__ __launch_bounds__(256) void k_out(const float* __restrict__ featp,
                                             const float* __restrict__ We,
                                             const float* __restrict__ Wout,
                                             const float* __restrict__ bout,
                                             float* __restrict__ out) {
    __shared__ float f[NHEADS * 257];
    __shared__ float bhrs[512];
    __shared__ float dxs[256];
    int b = blockIdx.x, t = threadIdx.x;
    for (int j = 0; j < NHEADS; ++j) {
        float s = 0.0f;
#pragma unroll
        for (int ns = 0; ns < 4; ++ns)
            s += featp[(((size_t)ns * B_ + b) * NHEADS + j) * D_ + t];
        f[j * 257 + t] = s;
    }
    __syncthreads();
    for (int rep = 0; rep < 2; ++rep) {
        int idx = rep * 256 + t;
        int j = idx >> 4, r = idx & 15;
        const float* w = We + (size_t)r * D_;
        const float* ff = &f[j * 257];
        float acc = 0.0f;
        for (int d = 0; d < D_; ++d) acc = fmaf(ff[d], w[d], acc);
        bhrs[idx] = acc;
    }
    __syncthreads();
    {
        int h = t >> 4, r = t & 15;
        dxs[t] = bhrs[h * 16 + r] - bhrs[(16 + h) * 16 + r];
    }
    __syncthreads();
    float acc = bout[t];
    const float* wrow = Wout + (size_t)t * 256;
    for (int c = 0; c < 256; ++c) acc = fmaf(dxs[c], wrow[c], acc);
    out[(size_t)b * D_ + t] = acc >= 0.0f ? acc : 0.01f * acc;
}

extern "C" void kernel_launch(void* const* d_in, const int* in_sizes, int n_in,
                              void* d_out, int out_size, void* d_ws, size_t ws_size,
                              hipStream_t stream) {
    const float* inp  = (const float*)d_in[0];
    // d_in[1] = batch_ids (equal-size contiguous graphs; structure used directly)
    const float* Wk   = (const float*)d_in[2];
    const float* Wq0  = (const float*)d_in[3];
    const float* Wq1  = (const float*)d_in[4];
    const float* We   = (const float*)d_in[5];
    const float* Wout = (const float*)d_in[6];
    const float* bout = (const float*)d_in[7];
    float* out = (float*)d_out;
    float* ws  = (float*)d_ws;
    float* pooled = ws + POOLED_OFF;
    float* P      = ws + P_OFF;
    float* logits = ws + LOG_OFF;     // reused in-place as att after k_softmax
    float* featp  = ws + FEATP_OFF;

    k_init<<<dim3(128), dim3(256), 0, stream>>>(pooled);
    k_pool<<<dim3(2048), dim3(256), 0, stream>>>(inp, pooled);
    k_qp<<<dim3(128), dim3(256), 0, stream>>>(pooled, Wq0, Wq1, Wk, P);
    k_logits<<<dim3(512), dim3(256), 0, stream>>>(inp, P, logits);
    k_softmax<<<dim3(4096), dim3(256), 0, stream>>>(logits);
    k_feat<<<dim3(512), dim3(256), 0, stream>>>(inp, logits, featp);
    k_out<<<dim3(128), dim3(256), 0, stream>>>(featp, We, Wout, bout, out);
}

// Round 2
// 664.440 us; speedup vs baseline: 1.0223x; 1.0223x over previous
//
#include <hip/hip_runtime.h>
#include <math.h>

#define B_ 128
#define N_ 2048
#define D_ 256
#define NHEADS 32   // 2 head-sets * 16 heads

// ws layout (float offsets)
#define POOLED_OFF 0                         // B*D = 32768
#define P_OFF      32768                     // B*32*256 = 1048576
#define E_OFF      1081344                   // bf16 E: B*32*2048 shorts = 4194304 floats
#define ML_OFF     5275648                   // B*32*4*2 = 32768
#define FEATP_OFF  5308416                   // 4*B*32*256 = 4194304  (end 9502720 fl = 38 MB)

__device__ __forceinline__ void atomic_max_f32(float* addr, float v) {
    if (v >= 0.0f) {
        atomicMax((int*)addr, __float_as_int(v + 0.0f));
    } else {
        atomicMin((unsigned int*)addr, __float_as_uint(v));
    }
}

__device__ __forceinline__ unsigned short f2bf(float f) {   // RNE bf16
    unsigned u = __float_as_uint(f);
    u += 0x7fff + ((u >> 16) & 1);
    return (unsigned short)(u >> 16);
}
__device__ __forceinline__ float bf2f(unsigned short h) {
    return __uint_as_float(((unsigned)h) << 16);
}

__global__ __launch_bounds__(256) void k_init(float* __restrict__ pooled) {
    pooled[blockIdx.x * 256 + threadIdx.x] = -INFINITY;
}

// global max-pool: grid B*16, block covers 128 rows; thread = 4 cols x 32 rows (float4)
__global__ __launch_bounds__(256) void k_pool(const float* __restrict__ inp,
                                              float* __restrict__ pooled) {
    int b = blockIdx.x >> 4;
    int ch = blockIdx.x & 15;
    int t = threadIdx.x;
    int sub = t >> 6;            // row phase 0..3
    int dq = (t & 63) * 4;       // column quad
    const float* p = inp + ((size_t)(b * N_ + ch * 128 + sub)) * D_ + dq;
    float4 m = {-INFINITY, -INFINITY, -INFINITY, -INFINITY};
#pragma unroll 8
    for (int i = 0; i < 32; ++i) {
        float4 v = *(const float4*)(p + (size_t)i * 4 * D_);
        m.x = fmaxf(m.x, v.x); m.y = fmaxf(m.y, v.y);
        m.z = fmaxf(m.z, v.z); m.w = fmaxf(m.w, v.w);
    }
    __shared__ float sm[4 * 256];
    sm[sub * 256 + dq + 0] = m.x;
    sm[sub * 256 + dq + 1] = m.y;
    sm[sub * 256 + dq + 2] = m.z;
    sm[sub * 256 + dq + 3] = m.w;
    __syncthreads();
    float v = fmaxf(fmaxf(sm[t], sm[256 + t]), fmaxf(sm[512 + t], sm[768 + t]));
    atomic_max_f32(pooled + b * D_ + t, v);
}

// q = pooled @ Wq^T (both sets), then P[b][j][d] = sum_k q[j][k] * Wk[k][d]
__global__ __launch_bounds__(256) void k_qp(const float* __restrict__ pooled,
                                            const float* __restrict__ Wq0,
                                            const float* __restrict__ Wq1,
                                            const float* __restrict__ Wk,
                                            float* __restrict__ P) {
    __shared__ float pl[D_];
    __shared__ float ql[1024];
    int b = blockIdx.x, t = threadIdx.x;
    pl[t] = pooled[b * D_ + t];
    __syncthreads();
    for (int rep = 0; rep < 4; ++rep) {
        int idx = rep * 256 + t;                 // 0..1023
        const float* Wq = (idx < 512) ? Wq0 : Wq1;
        int row = idx & 511;
        const float4* wr = (const float4*)(Wq + (size_t)row * D_);
        float acc = 0.0f;
        for (int dq = 0; dq < 64; ++dq) {
            float4 w = wr[dq];
            const float* pp = &pl[dq * 4];
            acc += w.x * pp[0] + w.y * pp[1] + w.z * pp[2] + w.w * pp[3];
        }
        ql[idx] = acc;
    }
    __syncthreads();
    float wk[32];
#pragma unroll
    for (int k = 0; k < 32; ++k) wk[k] = Wk[k * D_ + t];
    for (int j = 0; j < NHEADS; ++j) {
        const float* q = &ql[(j >> 4) * 512 + (j & 15) * 32];
        float acc = 0.0f;
#pragma unroll
        for (int k = 0; k < 32; ++k) acc = fmaf(q[k], wk[k], acc);
        P[((size_t)b * NHEADS + j) * D_ + t] = acc;
    }
}

// logits + chunk-local softmax stats: s[b][j][n] = sum_d P[b][j][d]*x[b][n][d]
// writes E = exp(s - m_chunk) in bf16, and (m, l) per (b, j, chunk).
// block tile: 512 n x 32 j, K chunked by 16; thread: 8n (stride 64) x 8j (stride 4)
__global__ __launch_bounds__(256) void k_logits_e(const float* __restrict__ inp,
                                                  const float* __restrict__ P,
                                                  unsigned short* __restrict__ E,
                                                  float* __restrict__ ml) {
    __shared__ float xs[512 * 20];   // [n][16 + 4 pad]; reused for reductions after K-loop
    __shared__ float ps[NHEADS * 20];
    int b = blockIdx.x >> 2, nt = blockIdx.x & 3;
    int n0 = nt * 512;
    int t = threadIdx.x;
    int jg = t & 3, ng = t >> 2;                 // j = jg + 4*jj ; n = ng + 64*k
    float acc[8][8] = {};                        // [jj][k]
    const float* xbase = inp + ((size_t)(b * N_ + n0)) * D_;
    const float* pbase = P + (size_t)b * NHEADS * D_;
    for (int c = 0; c < 16; ++c) {
        int d0 = c * 16;
        {   // stage x: 512 rows x 16 d
            int q = t & 3, nrow = t >> 2;
            for (int k = 0; k < 8; ++k) {
                int n = nrow + k * 64;
                float4 v = *(const float4*)(xbase + (size_t)n * D_ + d0 + q * 4);
                *(float4*)&xs[n * 20 + q * 4] = v;
            }
            if (t < 128) {
                int j = t >> 2;
                float4 v = *(const float4*)(pbase + (size_t)j * D_ + d0 + q * 4);
                *(float4*)&ps[j * 20 + q * 4] = v;
            }
        }
        __syncthreads();
#pragma unroll
        for (int dd = 0; dd < 16; dd += 4) {
            float4 xa[8], pa[8];
#pragma unroll
            for (int k = 0; k < 8; ++k)
                xa[k] = *(const float4*)&xs[(ng + 64 * k) * 20 + dd];
#pragma unroll
            for (int jj = 0; jj < 8; ++jj)
                pa[jj] = *(const float4*)&ps[(jg + 4 * jj) * 20 + dd];
#pragma unroll
            for (int jj = 0; jj < 8; ++jj)
#pragma unroll
                for (int k = 0; k < 8; ++k)
                    acc[jj][k] += xa[k].x * pa[jj].x + xa[k].y * pa[jj].y +
                                  xa[k].z * pa[jj].z + xa[k].w * pa[jj].w;
        }
        __syncthreads();
    }
    // ---- chunk softmax stats (reuse xs as scratch) ----
    float* red  = xs;            // [32][64]
    float* red2 = xs + 2048;     // [32][8]
    float* mrow = xs + 2048 + 256;   // [32]
    int jr = t >> 3, pr = t & 7;
    // per-thread max over k, reduce across the 64 ng's per j
#pragma unroll
    for (int jj = 0; jj < 8; ++jj) {
        float lm = acc[jj][0];
#pragma unroll
        for (int k = 1; k < 8; ++k) lm = fmaxf(lm, acc[jj][k]);
        red[(jg + 4 * jj) * 64 + ng] = lm;
    }
    __syncthreads();
    {
        float v = red[jr * 64 + pr * 8];
#pragma unroll
        for (int i = 1; i < 8; ++i) v = fmaxf(v, red[jr * 64 + pr * 8 + i]);
        red2[jr * 8 + pr] = v;
    }
    __syncthreads();
    if (t < 32) {
        float v = red2[t * 8];
#pragma unroll
        for (int i = 1; i < 8; ++i) v = fmaxf(v, red2[t * 8 + i]);
        mrow[t] = v;
    }
    __syncthreads();
    // exp, write E (bf16), accumulate sums
#pragma unroll
    for (int jj = 0; jj < 8; ++jj) {
        int j = jg + 4 * jj;
        float m = mrow[j];
        unsigned short* Eb = E + ((size_t)b * NHEADS + j) * N_ + n0 + ng;
        float s = 0.0f;
#pragma unroll
        for (int k = 0; k < 8; ++k) {
            float e = __expf(acc[jj][k] - m);
            s += e;
            Eb[64 * k] = f2bf(e);
        }
        red[j * 64 + ng] = s;
    }
    __syncthreads();
    {
        float v = 0.0f;
#pragma unroll
        for (int i = 0; i < 8; ++i) v += red[jr * 64 + pr * 8 + i];
        red2[jr * 8 + pr] = v;
    }
    __syncthreads();
    if (t < 32) {
        float v = 0.0f;
#pragma unroll
        for (int i = 0; i < 8; ++i) v += red2[t * 8 + i];
        float* mlp = ml + (((size_t)b * NHEADS + t) * 4 + nt) * 2;
        mlp[0] = mrow[t];
        mlp[1] = v;
    }
}

// feat partials: featp[ns][b][j][d] = sum_{n in chunk ns} wc_j * E[b][j][n] * x[b][n][d]
// wc_j = exp(m_ns - M_j). grid = B*4; thread: 4j x 8d
__global__ __launch_bounds__(256) void k_feat(const float* __restrict__ inp,
                                              const unsigned short* __restrict__ E,
                                              const float* __restrict__ ml,
                                              float* __restrict__ featp) {
    __shared__ float xs[32 * 256];
    __shared__ float as_[32 * 36];
    __shared__ float wcs[32];
    int b = blockIdx.x >> 2, ns = blockIdx.x & 3;
    int n0 = ns * 512;
    int t = threadIdx.x;
    int dg = t & 31, jg = t >> 5;                     // j = jg*4 + jj
    if (t < 32) {
        const float* mlb = ml + ((size_t)b * NHEADS + t) * 8;
        float M = fmaxf(fmaxf(mlb[0], mlb[2]), fmaxf(mlb[4], mlb[6]));
        wcs[t] = __expf(mlb[ns * 2] - M);
    }
    float4 accA[4] = {};
    float4 accB[4] = {};
    const float* xb = inp + ((size_t)(b * N_ + n0)) * D_;
    const unsigned short* eb0 = E + (size_t)b * NHEADS * N_ + n0;
    __syncthreads();
    int js = t >> 3, qq = t & 7;
    float wj = wcs[js];
    const unsigned short* ebj = eb0 + (size_t)js * N_ + qq * 4;
    for (int c = 0; c < 16; ++c) {
        {   // stage 32 rows of x (contiguous) + 32x32 weighted att
            int q = t & 63, row = t >> 6;
            for (int k = 0; k < 8; ++k) {
                int n = row + k * 4;
                *(float4*)&xs[n * 256 + q * 4] =
                    *(const float4*)(xb + (size_t)(c * 32 + n) * D_ + q * 4);
            }
            ushort4 ev = *(const ushort4*)(ebj + c * 32);
            float4 av = {bf2f(ev.x) * wj, bf2f(ev.y) * wj,
                         bf2f(ev.z) * wj, bf2f(ev.w) * wj};
            *(float4*)&as_[js * 36 + qq * 4] = av;
        }
        __syncthreads();
#pragma unroll
        for (int nn = 0; nn < 32; nn += 4) {
            float4 aa[4];
#pragma unroll
            for (int jj = 0; jj < 4; ++jj)
                aa[jj] = *(const float4*)&as_[(jg * 4 + jj) * 36 + nn];
#pragma unroll
            for (int i4 = 0; i4 < 4; ++i4) {
                int n = nn + i4;
                float4 xA = *(const float4*)&xs[n * 256 + dg * 4];
                float4 xB = *(const float4*)&xs[n * 256 + 128 + dg * 4];
#pragma unroll
                for (int jj = 0; jj < 4; ++jj) {
                    float a = (i4 == 0) ? aa[jj].x : (i4 == 1) ? aa[jj].y
                            : (i4 == 2) ? aa[jj].z : aa[jj].w;
                    accA[jj].x = fmaf(a, xA.x, accA[jj].x);
                    accA[jj].y = fmaf(a, xA.y, accA[jj].y);
                    accA[jj].z = fmaf(a, xA.z, accA[jj].z);
                    accA[jj].w = fmaf(a, xA.w, accA[jj].w);
                    accB[jj].x = fmaf(a, xB.x, accB[jj].x);
                    accB[jj].y = fmaf(a, xB.y, accB[jj].y);
                    accB[jj].z = fmaf(a, xB.z, accB[jj].z);
                    accB[jj].w = fmaf(a, xB.w, accB[jj].w);
                }
            }
        }
        __syncthreads();
    }
    float* fb = featp + ((size_t)ns * B_ + b) * NHEADS * D_;
#pragma unroll
    for (int jj = 0; jj < 4; ++jj) {
        int j = jg * 4 + jj;
        *(float4*)(fb + (size_t)j * D_ + dg * 4) = accA[jj];
        *(float4*)(fb + (size_t)j * D_ + 128 + dg * 4) = accB[jj];
    }
}

// epilogue: merge partials (x 1/L), bhr = feat@We^T, dx, out = dx@Wout^T + bias, leaky
__global__ __launch_bounds__(256) void k_out(const float* __restrict__ featp,
                                             const float* __restrict__ ml,
                                             const float* __restrict__ We,
                                             const float* __restrict__ Wout,
                                             const float* __restrict__ bout,
                                             float* __restrict__ out) {
    __shared__ float f[NHEADS * 257];
    __shared__ float bhrs[512];
    __shared__ float dxs[256];
    __shared__ float linv[NHEADS];
    int b = blockIdx.x, t = threadIdx.x;
    if (t < 32) {
        const float* mlb = ml + ((size_t)b * NHEADS + t) * 8;
        float M = fmaxf(fmaxf(mlb[0], mlb[2]), fmaxf(mlb[4], mlb[6]));
        float L = __expf(mlb[0] - M) * mlb[1] + __expf(mlb[2] - M) * mlb[3] +
                  __expf(mlb[4] - M) * mlb[5] + __expf(mlb[6] - M) * mlb[7];
        linv[t] = 1.0f / L;
    }
    __syncthreads();
    for (int j = 0; j < NHEADS; ++j) {
        float s = 0.0f;
#pragma unroll
        for (int ns = 0; ns < 4; ++ns)
            s += featp[(((size_t)ns * B_ + b) * NHEADS + j) * D_ + t];
        f[j * 257 + t] = s * linv[j];
    }
    __syncthreads();
    for (int rep = 0; rep < 2; ++rep) {
        int idx = rep * 256 + t;
        int j = idx >> 4, r = idx & 15;
        const float* w = We + (size_t)r * D_;
        const float* ff = &f[j * 257];
        float acc = 0.0f;
        for (int d = 0; d < D_; ++d) acc = fmaf(ff[d], w[d], acc);
        bhrs[idx] = acc;
    }
    __syncthreads();
    {
        int h = t >> 4, r = t & 15;
        dxs[t] = bhrs[h * 16 + r] - bhrs[(16 + h) * 16 + r];
    }
    __syncthreads();
    float acc = bout[t];
    const float* wrow = Wout + (size_t)t * 256;
    for (int c = 0; c < 256; ++c) acc = fmaf(dxs[c], wrow[c], acc);
    out[(size_t)b * D_ + t] = acc >= 0.0f ? acc : 0.01f * acc;
}

extern "C" void kernel_launch(void* const* d_in, const int* in_sizes, int n_in,
                              void* d_out, int out_size, void* d_ws, size_t ws_size,
                              hipStream_t stream) {
    const float* inp  = (const float*)d_in[0];
    // d_in[1] = batch_ids (equal-size contiguous graphs; structure used directly)
    const float* Wk   = (const float*)d_in[2];
    const float* Wq0  = (const float*)d_in[3];
    const float* Wq1  = (const float*)d_in[4];
    const float* We   = (const float*)d_in[5];
    const float* Wout = (const float*)d_in[6];
    const float* bout = (const float*)d_in[7];
    float* out = (float*)d_out;
    float* ws  = (float*)d_ws;
    float* pooled = ws + POOLED_OFF;
    float* P      = ws + P_OFF;
    unsigned short* E = (unsigned short*)(ws + E_OFF);
    float* ml     = ws + ML_OFF;
    float* featp  = ws + FEATP_OFF;

    k_init<<<dim3(128), dim3(256), 0, stream>>>(pooled);
    k_pool<<<dim3(2048), dim3(256), 0, stream>>>(inp, pooled);
    k_qp<<<dim3(128), dim3(256), 0, stream>>>(pooled, Wq0, Wq1, Wk, P);
    k_logits_e<<<dim3(512), dim3(256), 0, stream>>>(inp, P, E, ml);
    k_feat<<<dim3(512), dim3(256), 0, stream>>>(inp, E, ml, featp);
    k_out<<<dim3(128), dim3(256), 0, stream>>>(featp, ml, We, Wout, bout, out);
}

// Round 3
// 609.410 us; speedup vs baseline: 1.1146x; 1.0903x over previous
//
#include <hip/hip_runtime.h>
#include <math.h>

#define B_ 128
#define N_ 2048
#define D_ 256
#define NHEADS 32   // 2 head-sets * 16 heads

// ws layout (float offsets)
#define POOLED_OFF 0              // 32768
#define PHI_OFF    32768          // B*32*256 ushort = 524288 fl
#define PLO_OFF    557056         // 524288 fl
#define ML_OFF     1081344        // B*32*4*2 = 32768
#define FEATP_OFF  1114112        // 4*B*256*32 = 4194304 (d-major!)
#define XHI_OFF    5308416        // B*N*256 ushort = 33554432 fl
#define XLO_OFF    38862848       // 33554432 fl  (end 72417280 fl = 290 MB)

// LDS byte offsets inside the 64 KB block of k_attn
#define XHI_S 0            // phase1: 512 rows x 32 bf16 = 32768 B
#define XLO_S 32768        // phase1: 32768 B
#define ATT_S 0            // phase2/3: 32 h x 520 bf16 (stride 1040 B) = 33280 B
#define XT_S  33280        // phase3: 256 d x 40 bf16 (stride 80 B) = 20480 B
#define STAT_S 53760       // smax[4][32] + ssum[4][32] = 1024 B

typedef __attribute__((ext_vector_type(8))) short short8;
typedef __attribute__((ext_vector_type(4))) float f32x4;

__device__ __forceinline__ void atomic_max_f32(float* addr, float v) {
    if (v >= 0.0f) atomicMax((int*)addr, __float_as_int(v + 0.0f));
    else           atomicMin((unsigned int*)addr, __float_as_uint(v));
}
__device__ __forceinline__ unsigned short f2bf(float f) {   // RNE
    unsigned u = __float_as_uint(f);
    u += 0x7fff + ((u >> 16) & 1);
    return (unsigned short)(u >> 16);
}
__device__ __forceinline__ float bf2f(unsigned short h) {
    return __uint_as_float(((unsigned)h) << 16);
}
__device__ __forceinline__ unsigned pack2bf(float a, float b) {
    return (unsigned)f2bf(a) | ((unsigned)f2bf(b) << 16);
}

__global__ __launch_bounds__(256) void k_init(float* __restrict__ pooled) {
    pooled[blockIdx.x * 256 + threadIdx.x] = -INFINITY;
}

// max-pool + write x as bf16 hi/lo. grid B*16; block covers 128 rows.
__global__ __launch_bounds__(256) void k_pool(const float* __restrict__ inp,
                                              float* __restrict__ pooled,
                                              unsigned short* __restrict__ xhi,
                                              unsigned short* __restrict__ xlo) {
    int b = blockIdx.x >> 4;
    int ch = blockIdx.x & 15;
    int t = threadIdx.x;
    int sub = t >> 6;            // row phase 0..3
    int dq = (t & 63) * 4;       // column quad
    const float* p = inp + ((size_t)(b * N_ + ch * 128 + sub)) * D_ + dq;
    size_t nodebase = (size_t)b * N_ + ch * 128 + sub;
    float4 m = {-INFINITY, -INFINITY, -INFINITY, -INFINITY};
#pragma unroll 4
    for (int i = 0; i < 32; ++i) {
        float4 v = *(const float4*)(p + (size_t)i * 4 * D_);
        m.x = fmaxf(m.x, v.x); m.y = fmaxf(m.y, v.y);
        m.z = fmaxf(m.z, v.z); m.w = fmaxf(m.w, v.w);
        size_t node = nodebase + (size_t)i * 4;
        ushort4 h4, l4;
        h4.x = f2bf(v.x); l4.x = f2bf(v.x - bf2f(h4.x));
        h4.y = f2bf(v.y); l4.y = f2bf(v.y - bf2f(h4.y));
        h4.z = f2bf(v.z); l4.z = f2bf(v.z - bf2f(h4.z));
        h4.w = f2bf(v.w); l4.w = f2bf(v.w - bf2f(h4.w));
        *(ushort4*)(xhi + node * D_ + dq) = h4;
        *(ushort4*)(xlo + node * D_ + dq) = l4;
    }
    __shared__ float sm[4 * 256];
    sm[sub * 256 + dq + 0] = m.x;
    sm[sub * 256 + dq + 1] = m.y;
    sm[sub * 256 + dq + 2] = m.z;
    sm[sub * 256 + dq + 3] = m.w;
    __syncthreads();
    float v = fmaxf(fmaxf(sm[t], sm[256 + t]), fmaxf(sm[512 + t], sm[768 + t]));
    atomic_max_f32(pooled + b * D_ + t, v);
}

// q = pooled @ Wq^T (both sets), P = q @ Wk -> bf16 hi/lo
__global__ __launch_bounds__(256) void k_qp(const float* __restrict__ pooled,
                                            const float* __restrict__ Wq0,
                                            const float* __restrict__ Wq1,
                                            const float* __restrict__ Wk,
                                            unsigned short* __restrict__ Phi,
                                            unsigned short* __restrict__ Plo) {
    __shared__ float pl[D_];
    __shared__ float ql[1024];
    int b = blockIdx.x, t = threadIdx.x;
    pl[t] = pooled[b * D_ + t];
    __syncthreads();
    for (int rep = 0; rep < 4; ++rep) {
        int idx = rep * 256 + t;                 // 0..1023
        const float* Wq = (idx < 512) ? Wq0 : Wq1;
        int row = idx & 511;
        const float4* wr = (const float4*)(Wq + (size_t)row * D_);
        float acc = 0.0f;
        for (int dqi = 0; dqi < 64; ++dqi) {
            float4 w = wr[dqi];
            const float* pp = &pl[dqi * 4];
            acc += w.x * pp[0] + w.y * pp[1] + w.z * pp[2] + w.w * pp[3];
        }
        ql[idx] = acc;
    }
    __syncthreads();
    float wk[32];
#pragma unroll
    for (int k = 0; k < 32; ++k) wk[k] = Wk[k * D_ + t];
    for (int j = 0; j < NHEADS; ++j) {
        const float* q = &ql[(j >> 4) * 512 + (j & 15) * 32];
        float acc = 0.0f;
#pragma unroll
        for (int k = 0; k < 32; ++k) acc = fmaf(q[k], wk[k], acc);
        unsigned short hi = f2bf(acc);
        unsigned short lo = f2bf(acc - bf2f(hi));
        Phi[((size_t)b * NHEADS + j) * D_ + t] = hi;
        Plo[((size_t)b * NHEADS + j) * D_ + t] = lo;
    }
}

// Fused attention: S^T = x*P^T (MFMA, hi/lo), chunk softmax, O = att*x (MFMA).
// grid = B*4 (b, ns); block 256 = 4 waves; each block: 512 nodes, all 32 heads.
__global__ __launch_bounds__(256) void k_attn(const unsigned short* __restrict__ xhi,
                                              const unsigned short* __restrict__ xlo,
                                              const unsigned short* __restrict__ Phi,
                                              const unsigned short* __restrict__ Plo,
                                              float* __restrict__ ml,
                                              float* __restrict__ featp) {
    __shared__ uint4 smem4[4096];                 // 65536 B
    unsigned char* smem = (unsigned char*)smem4;
    float* smax = (float*)(smem + STAT_S);        // [4][32]
    float* ssum = (float*)(smem + STAT_S + 512);  // [4][32]

    int b = blockIdx.x >> 2, ns = blockIdx.x & 3;
    int t = threadIdx.x;
    int w = t >> 6;                // wave id 0..3
    int lane = t & 63;
    int lq = lane >> 4;            // quad 0..3
    int lm = lane & 15;
    size_t gnode0 = (size_t)b * N_ + ns * 512;

    // ---------------- phase 1: S^T accumulate ----------------
    f32x4 acc_s[8][2];
#pragma unroll
    for (int mt = 0; mt < 8; ++mt)
#pragma unroll
        for (int ht = 0; ht < 2; ++ht) acc_s[mt][ht] = (f32x4){0.f, 0.f, 0.f, 0.f};

    int srow = t >> 2, sseg = t & 3;
    for (int dc = 0; dc < 8; ++dc) {
        int d0 = dc * 32;
        // B-frags from global (L2-hot, tiny)
        short8 bh[2], bl[2];
#pragma unroll
        for (int ht = 0; ht < 2; ++ht) {
            size_t poff = ((size_t)b * NHEADS + ht * 16 + lm) * D_ + d0 + lq * 8;
            bh[ht] = *(const short8*)(Phi + poff);
            bl[ht] = *(const short8*)(Plo + poff);
        }
        // stage x hi/lo chunk: 512 rows x 32 els
        const unsigned short* gxh = xhi + (gnode0 + srow) * D_ + d0 + sseg * 8;
        const unsigned short* gxl = xlo + (gnode0 + srow) * D_ + d0 + sseg * 8;
        __syncthreads();   // protect LDS from previous iteration's readers
#pragma unroll
        for (int i = 0; i < 8; ++i) {
            *(uint4*)(smem + XHI_S + (size_t)(srow + i * 64) * 64 + sseg * 16) =
                *(const uint4*)(gxh + (size_t)i * 64 * D_);
            *(uint4*)(smem + XLO_S + (size_t)(srow + i * 64) * 64 + sseg * 16) =
                *(const uint4*)(gxl + (size_t)i * 64 * D_);
        }
        __syncthreads();
#pragma unroll
        for (int mt = 0; mt < 8; ++mt) {
            size_t roff = (size_t)(w * 128 + mt * 16 + lm) * 64 + lq * 16;
            short8 ah = *(const short8*)(smem + XHI_S + roff);
            short8 al = *(const short8*)(smem + XLO_S + roff);
#pragma unroll
            for (int ht = 0; ht < 2; ++ht) {
                acc_s[mt][ht] = __builtin_amdgcn_mfma_f32_16x16x32_bf16(ah, bh[ht], acc_s[mt][ht], 0, 0, 0);
                acc_s[mt][ht] = __builtin_amdgcn_mfma_f32_16x16x32_bf16(ah, bl[ht], acc_s[mt][ht], 0, 0, 0);
                acc_s[mt][ht] = __builtin_amdgcn_mfma_f32_16x16x32_bf16(al, bh[ht], acc_s[mt][ht], 0, 0, 0);
            }
        }
    }
    __syncthreads();   // done with x-LDS; att region reuses it

    // ---------------- phase 2: chunk softmax ----------------
    // lane holds S^T[n = w*128+mt*16+lq*4+r][h = ht*16+lm]
    float bm[2];
#pragma unroll
    for (int ht = 0; ht < 2; ++ht) {
        float m = -INFINITY;
#pragma unroll
        for (int mt = 0; mt < 8; ++mt) {
            m = fmaxf(m, fmaxf(fmaxf(acc_s[mt][ht][0], acc_s[mt][ht][1]),
                               fmaxf(acc_s[mt][ht][2], acc_s[mt][ht][3])));
        }
        m = fmaxf(m, __shfl_xor(m, 16));
        m = fmaxf(m, __shfl_xor(m, 32));
        if (lane < 16) smax[w * 32 + ht * 16 + lane] = m;
    }
    __syncthreads();
#pragma unroll
    for (int ht = 0; ht < 2; ++ht) {
        bm[ht] = fmaxf(fmaxf(smax[0 * 32 + ht * 16 + lm], smax[1 * 32 + ht * 16 + lm]),
                       fmaxf(smax[2 * 32 + ht * 16 + lm], smax[3 * 32 + ht * 16 + lm]));
    }
#pragma unroll
    for (int ht = 0; ht < 2; ++ht) {
        float s = 0.0f;
#pragma unroll
        for (int mt = 0; mt < 8; ++mt) {
            float e0 = __expf(acc_s[mt][ht][0] - bm[ht]);
            float e1 = __expf(acc_s[mt][ht][1] - bm[ht]);
            float e2 = __expf(acc_s[mt][ht][2] - bm[ht]);
            float e3 = __expf(acc_s[mt][ht][3] - bm[ht]);
            s += (e0 + e1) + (e2 + e3);
            uint2 pk;
            pk.x = pack2bf(e0, e1);
            pk.y = pack2bf(e2, e3);
            *(uint2*)(smem + ATT_S + (size_t)(ht * 16 + lm) * 1040 +
                      (size_t)(w * 128 + mt * 16 + lq * 4) * 2) = pk;
        }
        s += __shfl_xor(s, 16);
        s += __shfl_xor(s, 32);
        if (lane < 16) ssum[w * 32 + ht * 16 + lane] = s;
    }
    __syncthreads();
    if (t < 32) {
        float mB = fmaxf(fmaxf(smax[t], smax[32 + t]), fmaxf(smax[64 + t], smax[96 + t]));
        float l = ssum[t] + ssum[32 + t] + ssum[64 + t] + ssum[96 + t];
        float* mlp = ml + (((size_t)b * NHEADS + t) * 4 + ns) * 2;
        mlp[0] = mB;
        mlp[1] = l;
    }
    __syncthreads();   // stats region about to be overwritten by xT staging

    // ---------------- phase 3: O = att * x (MFMA) ----------------
    f32x4 acc_o[2][4];
#pragma unroll
    for (int mt = 0; mt < 2; ++mt)
#pragma unroll
        for (int dt = 0; dt < 4; ++dt) acc_o[mt][dt] = (f32x4){0.f, 0.f, 0.f, 0.f};

    int db = t & 31, nb = t >> 5;          // staging: d-block 8, n-block 4
    for (int c = 0; c < 16; ++c) {
        // load 4 rows x 8 d, transpose in regs, store x^T chunk [256 d][32 n]
        const unsigned short* gx = xhi + (gnode0 + c * 32 + nb * 4) * D_ + db * 8;
        uint4 R0 = *(const uint4*)(gx);
        uint4 R1 = *(const uint4*)(gx + D_);
        uint4 R2 = *(const uint4*)(gx + 2 * D_);
        uint4 R3 = *(const uint4*)(gx + 3 * D_);
        const unsigned* r0 = (const unsigned*)&R0;
        const unsigned* r1 = (const unsigned*)&R1;
        const unsigned* r2 = (const unsigned*)&R2;
        const unsigned* r3 = (const unsigned*)&R3;
        uint2 T[8];
#pragma unroll
        for (int c2 = 0; c2 < 4; ++c2) {
            T[2 * c2 + 0].x = __builtin_amdgcn_perm(r1[c2], r0[c2], 0x05040100u);
            T[2 * c2 + 0].y = __builtin_amdgcn_perm(r3[c2], r2[c2], 0x05040100u);
            T[2 * c2 + 1].x = __builtin_amdgcn_perm(r1[c2], r0[c2], 0x07060302u);
            T[2 * c2 + 1].y = __builtin_amdgcn_perm(r3[c2], r2[c2], 0x07060302u);
        }
        __syncthreads();   // previous chunk's MFMA reads done
#pragma unroll
        for (int j = 0; j < 8; ++j) {
            int jj = (j + db) & 7;   // stagger to spread banks
            *(uint2*)(smem + XT_S + (size_t)(db * 8 + jj) * 80 + nb * 8) = T[jj];
        }
        __syncthreads();
        // MFMA: K = 32 nodes of this chunk
        short8 a0 = *(const short8*)(smem + ATT_S + (size_t)lm * 1040 + (size_t)(c * 32 + lq * 8) * 2);
        short8 a1 = *(const short8*)(smem + ATT_S + (size_t)(16 + lm) * 1040 + (size_t)(c * 32 + lq * 8) * 2);
#pragma unroll
        for (int dt = 0; dt < 4; ++dt) {
            short8 bf = *(const short8*)(smem + XT_S + (size_t)(w * 64 + dt * 16 + lm) * 80 + lq * 16);
            acc_o[0][dt] = __builtin_amdgcn_mfma_f32_16x16x32_bf16(a0, bf, acc_o[0][dt], 0, 0, 0);
            acc_o[1][dt] = __builtin_amdgcn_mfma_f32_16x16x32_bf16(a1, bf, acc_o[1][dt], 0, 0, 0);
        }
    }
    // write featp (d-major: [ns][b][d][j]); C/D: col=lane&15 (d), row=lq*4+r (h)
    float* fb = featp + ((size_t)(ns * B_ + b)) * D_ * NHEADS;
#pragma unroll
    for (int mt = 0; mt < 2; ++mt)
#pragma unroll
        for (int dt = 0; dt < 4; ++dt) {
            int d = w * 64 + dt * 16 + lm;
            int h0 = mt * 16 + lq * 4;
            *(f32x4*)(fb + (size_t)d * NHEADS + h0) = acc_o[mt][dt];
        }
}

// epilogue: merge chunk partials, feat@We^T, dx, dx@Wout^T + bias, leaky
__global__ __launch_bounds__(256) void k_out(const float* __restrict__ featp,
                                             const float* __restrict__ ml,
                                             const float* __restrict__ We,
                                             const float* __restrict__ Wout,
                                             const float* __restrict__ bout,
                                             float* __restrict__ out) {
    __shared__ float f[NHEADS * 257];
    __shared__ float bhrs[512];
    __shared__ float dxs[256];
    __shared__ float wns[4 * 32];
    __shared__ float linv2[32];
    int b = blockIdx.x, t = threadIdx.x;
    if (t < 32) {
        const float* mlb = ml + ((size_t)b * NHEADS + t) * 8;
        float M = fmaxf(fmaxf(mlb[0], mlb[2]), fmaxf(mlb[4], mlb[6]));
        float e0 = __expf(mlb[0] - M), e1 = __expf(mlb[2] - M);
        float e2 = __expf(mlb[4] - M), e3 = __expf(mlb[6] - M);
        float L = e0 * mlb[1] + e1 * mlb[3] + e2 * mlb[5] + e3 * mlb[7];
        wns[0 * 32 + t] = e0; wns[1 * 32 + t] = e1;
        wns[2 * 32 + t] = e2; wns[3 * 32 + t] = e3;
        linv2[t] = 1.0f / L;
    }
    __syncthreads();
    float fj[32];
#pragma unroll
    for (int j = 0; j < 32; ++j) fj[j] = 0.0f;
#pragma unroll
    for (int ns = 0; ns < 4; ++ns) {
        const float* fp = featp + ((size_t)(ns * B_ + b) * D_ + t) * NHEADS;
#pragma unroll
        for (int j4 = 0; j4 < 8; ++j4) {
            float4 v = *(const float4*)(fp + j4 * 4);
            fj[j4 * 4 + 0] += wns[ns * 32 + j4 * 4 + 0] * v.x;
            fj[j4 * 4 + 1] += wns[ns * 32 + j4 * 4 + 1] * v.y;
            fj[j4 * 4 + 2] += wns[ns * 32 + j4 * 4 + 2] * v.z;
            fj[j4 * 4 + 3] += wns[ns * 32 + j4 * 4 + 3] * v.w;
        }
    }
#pragma unroll
    for (int j = 0; j < 32; ++j) f[j * 257 + t] = fj[j] * linv2[j];
    __syncthreads();
    for (int rep = 0; rep < 2; ++rep) {
        int idx = rep * 256 + t;
        int j = idx >> 4, r = idx & 15;
        const float* wrow = We + (size_t)r * D_;
        const float* ff = &f[j * 257];
        float acc = 0.0f;
        for (int d = 0; d < D_; ++d) acc = fmaf(ff[d], wrow[d], acc);
        bhrs[idx] = acc;
    }
    __syncthreads();
    {
        int h = t >> 4, r = t & 15;
        dxs[t] = bhrs[h * 16 + r] - bhrs[(16 + h) * 16 + r];
    }
    __syncthreads();
    float acc = bout[t];
    const float* wrow = Wout + (size_t)t * 256;
    for (int c = 0; c < 256; ++c) acc = fmaf(dxs[c], wrow[c], acc);
    out[(size_t)b * D_ + t] = acc >= 0.0f ? acc : 0.01f * acc;
}

extern "C" void kernel_launch(void* const* d_in, const int* in_sizes, int n_in,
                              void* d_out, int out_size, void* d_ws, size_t ws_size,
                              hipStream_t stream) {
    const float* inp  = (const float*)d_in[0];
    // d_in[1] = batch_ids (equal-size contiguous graphs)
    const float* Wk   = (const float*)d_in[2];
    const float* Wq0  = (const float*)d_in[3];
    const float* Wq1  = (const float*)d_in[4];
    const float* We   = (const float*)d_in[5];
    const float* Wout = (const float*)d_in[6];
    const float* bout = (const float*)d_in[7];
    float* out = (float*)d_out;
    float* ws  = (float*)d_ws;
    float* pooled = ws + POOLED_OFF;
    unsigned short* Phi = (unsigned short*)(ws + PHI_OFF);
    unsigned short* Plo = (unsigned short*)(ws + PLO_OFF);
    float* ml     = ws + ML_OFF;
    float* featp  = ws + FEATP_OFF;
    unsigned short* xhi = (unsigned short*)(ws + XHI_OFF);
    unsigned short* xlo = (unsigned short*)(ws + XLO_OFF);

    k_init<<<dim3(128), dim3(256), 0, stream>>>(pooled);
    k_pool<<<dim3(2048), dim3(256), 0, stream>>>(inp, pooled, xhi, xlo);
    k_qp<<<dim3(128), dim3(256), 0, stream>>>(pooled, Wq0, Wq1, Wk, Phi, Plo);
    k_attn<<<dim3(512), dim3(256), 0, stream>>>(xhi, xlo, Phi, Plo, ml, featp);
    k_out<<<dim3(128), dim3(256), 0, stream>>>(featp, ml, We, Wout, bout, out);
}